// Round 6
// baseline (72.879 us; speedup 1.0000x reference)
//
#include <hip/hip_runtime.h>
#include <stdint.h>

// out[b, q*16+c, do,ho,wo] = sum_{kd,kh,kw} x[b, q*16+c, do+kd-1, ho+kh-1, wo+kw-1]
//                                           * weight[b, 0, c, (kd*3+kh)*3+kw, do,ho,wo]
// x: (2,64,16,64,64) f32; weight: (2,1,16,27,16,64,64) f32; out: (2,64,16,64,64) f32
//
// Block = 512 threads, 2 teams x 256: douts {2a, 2a+1} for one (b,c,ho_tile).
// All 4 x-planes (2a-1..2a+2) staged upfront via global_load_lds (72 KB LDS),
// ONE barrier, then straight-line compute: 27 nontemporal weight loads/thread
// with no barriers/drains. 2 blocks/CU = 16 waves/CU.

#define NQ 4
typedef float f4_t __attribute__((ext_vector_type(4)));

#define BUF_FLOATS (NQ * 18 * 64)              // 4608 floats per plane-slab
#define LDS_FLOATS (16 + 4 * BUF_FLOATS + 16)  // guards for W-edge reads

__device__ __forceinline__ void async_copy16(const float* gsrc, float* ldst) {
    __builtin_amdgcn_global_load_lds(
        (const __attribute__((address_space(1))) uint32_t*)gsrc,
        (__attribute__((address_space(3))) uint32_t*)ldst, 16, 0, 0);
}

__global__ __launch_bounds__(512, 4) void lconv_kernel(
    const float* __restrict__ x, const float* __restrict__ wt, float* __restrict__ out,
    const float* __restrict__ zp)
{
    __shared__ __align__(16) float lds_raw[LDS_FLOATS];

    const int tid  = threadIdx.x;
    const int team = tid >> 8;        // 0/1: which dout of the pair
    const int t    = tid & 255;
    const int tw   = t & 15;          // group of 4 wo
    const int th   = t >> 4;          // ho row within tile

    // XCD-aware decode: bid&7 = XCD; each XCD owns 4 (b,c) slices.
    const int bid   = blockIdx.x;
    const int slot  = bid >> 3;                 // 0..127
    const int bc    = (bid & 7) * 4 + (slot >> 5);
    const int apair = (slot >> 2) & 7;
    const int ho_tile = slot & 3;
    const int b = bc >> 4, c = bc & 15;

    const int ho_base = ho_tile * 16;
    const int ho  = ho_base + th;
    const int wo0 = tw * 4;
    const int d0  = apair * 2;        // douts d0, d0+1; planes d0-1 .. d0+2

    const float* xbase = x + ((size_t)(b * 64 + c) * 16) * 4096;

    // ---- stage all 4 planes: 4608 16B-chunks over 512 threads (9 each) ----
    // Wave-contiguity: 1152 % 64 == 0, so p and buf are wave-uniform and the
    // LDS dest is wave-base + lane*16 within every wave.
    #pragma unroll
    for (int it = 0; it < 9; ++it) {
        const int i   = it * 512 + tid;        // 0..4607
        const int p   = i / 1152;              // plane 0..3
        const int r2  = i - p * 1152;          // chunk within plane
        const int row = r2 >> 4;               // q*18 + hl
        const int seg = r2 & 15;
        const int q   = row / 18;
        const int hl  = row - q * 18;
        const int gh  = ho_base - 1 + hl;
        const int d   = d0 - 1 + p;
        const bool ok = ((unsigned)d < 16u) && ((unsigned)gh < 64u);
        const float* src = ok
            ? (xbase + (size_t)q * 1048576 + (size_t)d * 4096 + (size_t)gh * 64 + seg * 4)
            : (zp + seg * 4);                  // zero page: D-pad and H-pad
        const int buf = (d + 1) & 3;
        async_copy16(src, &lds_raw[16 + buf * BUF_FLOATS + r2 * 4]);
    }
    __syncthreads();   // the ONLY barrier (drains staging vmcnt)

    const int dout = d0 + team;

    const float* wbase = wt + (((size_t)(b * 16 + c) * 27) * 16 + dout) * 4096
                            + (size_t)ho * 64 + wo0;

    float acc[NQ][4];
    #pragma unroll
    for (int q = 0; q < NQ; ++q)
        #pragma unroll
        for (int j = 0; j < 4; ++j) acc[q][j] = 0.f;

    #pragma unroll
    for (int dd = 0; dd < 3; ++dd) {
        const int buf = (dout + dd) & 3;       // plane dout-1+dd (OOB planes = zeros)
        const float* bbase = &lds_raw[16 + buf * BUF_FLOATS];
        #pragma unroll
        for (int dh = 0; dh < 3; ++dh) {
            float xv[NQ][6];
            #pragma unroll
            for (int q = 0; q < NQ; ++q) {
                const float* r = bbase + (q * 18 + th + dh) * 64;
                const f4_t m = *reinterpret_cast<const f4_t*>(r + wo0);
                const float xl = r[wo0 - 1];       // const offsets -> ds_read2
                const float xr = r[wo0 + 4];
                xv[q][0] = (tw > 0)  ? xl : 0.f;   // W-pad by value mask
                xv[q][1] = m.x; xv[q][2] = m.y; xv[q][3] = m.z; xv[q][4] = m.w;
                xv[q][5] = (tw < 15) ? xr : 0.f;
            }
            #pragma unroll
            for (int dw = 0; dw < 3; ++dw) {
                const int k = (dd * 3 + dh) * 3 + dw;
                const f4_t w4 = __builtin_nontemporal_load(
                    reinterpret_cast<const f4_t*>(wbase + (size_t)k * 65536));
                #pragma unroll
                for (int q = 0; q < NQ; ++q) {
                    acc[q][0] = fmaf(xv[q][0 + dw], w4.x, acc[q][0]);
                    acc[q][1] = fmaf(xv[q][1 + dw], w4.y, acc[q][1]);
                    acc[q][2] = fmaf(xv[q][2 + dw], w4.z, acc[q][2]);
                    acc[q][3] = fmaf(xv[q][3 + dw], w4.w, acc[q][3]);
                }
            }
        }
    }

    #pragma unroll
    for (int q = 0; q < NQ; ++q) {
        float* orow = out + ((size_t)(b * 64 + q * 16 + c) * 16 + dout) * 4096
                          + (size_t)ho * 64 + wo0;
        f4_t rr; rr.x = acc[q][0]; rr.y = acc[q][1]; rr.z = acc[q][2]; rr.w = acc[q][3];
        __builtin_nontemporal_store(rr, reinterpret_cast<f4_t*>(orow));
    }
}

extern "C" void kernel_launch(void* const* d_in, const int* in_sizes, int n_in,
                              void* d_out, int out_size, void* d_ws, size_t ws_size,
                              hipStream_t stream) {
    const float* x  = (const float*)d_in[0];
    const float* wt = (const float*)d_in[1];
    float* out      = (float*)d_out;

    // zero page for D/H-pad staging sources (graph-capture-safe async memset)
    hipMemsetAsync(d_ws, 0, 4096, stream);

    // 1024 blocks = 8 XCD x 4 bc x 8 apair x 4 ho_tile ; 512 threads
    dim3 grid(1024), block(512);
    hipLaunchKernelGGL(lconv_kernel, grid, block, 0, stream, x, wt, out,
                       (const float*)d_ws);
}

// Round 7
// 69.129 us; speedup vs baseline: 1.0542x; 1.0542x over previous
//
#include <hip/hip_runtime.h>
#include <stdint.h>

// out[b, q*16+c, do,ho,wo] = sum_{kd,kh,kw} x[b, q*16+c, do+kd-1, ho+kh-1, wo+kw-1]
//                                           * weight[b, 0, c, (kd*3+kh)*3+kw, do,ho,wo]
// x: (2,64,16,64,64) f32; weight: (2,1,16,27,16,64,64) f32; out: (2,64,16,64,64) f32
//
// r5 structure (256 thr, 2-buffer ping-pong, stage-ahead-1, barrier/section,
// global_load_lds staging, 4 blocks/CU) extended to 2 douts per block:
// 4 sections over planes 2a-1..2a+2; plane s -> dout_lo dd=s, dout_hi dd=s-1.

#define NQ 4
typedef float f4_t __attribute__((ext_vector_type(4)));

#define BUF_FLOATS (NQ * 18 * 64)              // 4608 floats per plane-slab
#define LDS_FLOATS (16 + 2 * BUF_FLOATS + 16)  // guards for W-edge reads

__device__ __forceinline__ void async_copy16(const float* gsrc, float* ldst) {
    __builtin_amdgcn_global_load_lds(
        (const __attribute__((address_space(1))) uint32_t*)gsrc,
        (__attribute__((address_space(3))) uint32_t*)ldst, 16, 0, 0);
}

__global__ __launch_bounds__(256) void lconv_kernel(
    const float* __restrict__ x, const float* __restrict__ wt, float* __restrict__ out,
    const float* __restrict__ zp)
{
    __shared__ __align__(16) float lds_raw[LDS_FLOATS];

    const int tid = threadIdx.x;
    const int tw  = tid & 15;   // group of 4 wo
    const int th  = tid >> 4;   // ho row within tile

    // XCD-aware decode: bid&7 = XCD; plane-sharing dout-pair blocks are 4 bids
    // apart inside one XCD slot group -> concurrent, L2-shared.
    const int bid   = blockIdx.x;            // 0..1023, full residency (4/CU)
    const int slot  = bid >> 3;              // 0..127
    const int bc    = (bid & 7) * 4 + (slot >> 5);
    const int a     = (slot >> 2) & 7;       // dout pair index
    const int ho_tile = slot & 3;
    const int b = bc >> 4, c = bc & 15;

    const int ho_base = ho_tile * 16;
    const int ho  = ho_base + th;
    const int wo0 = tw * 4;
    const int dlo = a * 2, dhi = dlo + 1;    // the two douts

    const float* xbase = x + ((size_t)(b * 64 + c) * 16) * 4096;

    // stage plane d into buf: 1152 16B chunks, linear LDS dest
    auto stage = [&](int buf, int d) {
        float* dbase = &lds_raw[16 + buf * BUF_FLOATS];
        #pragma unroll
        for (int it = 0; it < 5; ++it) {
            const int i = it * 256 + tid;
            if (it < 4 || i < 1152) {
                const int row = i >> 4;            // q*18 + hl
                const int seg = i & 15;
                const int q   = row / 18;
                const int hl  = row - q * 18;
                const int gh  = ho_base - 1 + hl;
                const bool ok = ((unsigned)d < 16u) && ((unsigned)gh < 64u);
                const float* src = ok
                    ? (xbase + (size_t)q * 1048576 + (size_t)d * 4096
                             + (size_t)gh * 64 + seg * 4)
                    : (zp + seg * 4);              // zero page: D-pad / H-pad
                async_copy16(src, dbase + (size_t)i * 4);
            }
        }
    };

    float accL[NQ][4], accH[NQ][4];
    #pragma unroll
    for (int q = 0; q < NQ; ++q)
        #pragma unroll
        for (int j = 0; j < 4; ++j) { accL[q][j] = 0.f; accH[q][j] = 0.f; }

    // weight bases at k=0 for the two douts
    const float* wlo = wt + (((size_t)(b * 16 + c) * 27) * 16 + dlo) * 4096
                          + (size_t)ho * 64 + wo0;
    const float* whi = wlo + 4096;   // dout+1

    stage(0, dlo - 1);
    __syncthreads();

    #pragma unroll
    for (int s = 0; s < 4; ++s) {              // plane d = dlo-1+s
        const int cur = s & 1, nxt = cur ^ 1;
        if (s < 3) stage(nxt, dlo + s);        // stage-ahead-1 (overlaps compute)

        const bool loA = (s < 3);              // dout_lo: dd = s
        const bool hiA = (s >= 1);             // dout_hi: dd = s-1
        const float* bbase = &lds_raw[16 + cur * BUF_FLOATS];

        #pragma unroll
        for (int dh = 0; dh < 3; ++dh) {
            f4_t wa[3], wb[3];
            #pragma unroll
            for (int dw = 0; dw < 3; ++dw) {
                if (loA) {
                    const int k = (s * 3 + dh) * 3 + dw;
                    wa[dw] = __builtin_nontemporal_load(
                        reinterpret_cast<const f4_t*>(wlo + (size_t)k * 65536));
                }
                if (hiA) {
                    const int k = ((s - 1) * 3 + dh) * 3 + dw;
                    wb[dw] = __builtin_nontemporal_load(
                        reinterpret_cast<const f4_t*>(whi + (size_t)k * 65536));
                }
            }
            #pragma unroll
            for (int q = 0; q < NQ; ++q) {
                const float* r = bbase + (q * 18 + th + dh) * 64;
                const f4_t m = *reinterpret_cast<const f4_t*>(r + wo0);
                const float xl = r[wo0 - 1];
                const float xr = r[wo0 + 4];
                float xv[6];
                xv[0] = (tw > 0)  ? xl : 0.f;   // W-pad by value mask
                xv[1] = m.x; xv[2] = m.y; xv[3] = m.z; xv[4] = m.w;
                xv[5] = (tw < 15) ? xr : 0.f;
                #pragma unroll
                for (int dw = 0; dw < 3; ++dw) {
                    if (loA) {
                        accL[q][0] = fmaf(xv[0 + dw], wa[dw].x, accL[q][0]);
                        accL[q][1] = fmaf(xv[1 + dw], wa[dw].y, accL[q][1]);
                        accL[q][2] = fmaf(xv[2 + dw], wa[dw].z, accL[q][2]);
                        accL[q][3] = fmaf(xv[3 + dw], wa[dw].w, accL[q][3]);
                    }
                    if (hiA) {
                        accH[q][0] = fmaf(xv[0 + dw], wb[dw].x, accH[q][0]);
                        accH[q][1] = fmaf(xv[1 + dw], wb[dw].y, accH[q][1]);
                        accH[q][2] = fmaf(xv[2 + dw], wb[dw].z, accH[q][2]);
                        accH[q][3] = fmaf(xv[3 + dw], wb[dw].w, accH[q][3]);
                    }
                }
            }
        }
        if (s < 3) __syncthreads();   // drains stage vmcnt + protects ping-pong
    }

    #pragma unroll
    for (int q = 0; q < NQ; ++q) {
        float* orowL = out + ((size_t)(b * 64 + q * 16 + c) * 16 + dlo) * 4096
                           + (size_t)ho * 64 + wo0;
        f4_t rl; rl.x = accL[q][0]; rl.y = accL[q][1]; rl.z = accL[q][2]; rl.w = accL[q][3];
        __builtin_nontemporal_store(rl, reinterpret_cast<f4_t*>(orowL));
        float* orowH = orowL + 4096;   // dout+1
        f4_t rh; rh.x = accH[q][0]; rh.y = accH[q][1]; rh.z = accH[q][2]; rh.w = accH[q][3];
        __builtin_nontemporal_store(rh, reinterpret_cast<f4_t*>(orowH));
    }
}

extern "C" void kernel_launch(void* const* d_in, const int* in_sizes, int n_in,
                              void* d_out, int out_size, void* d_ws, size_t ws_size,
                              hipStream_t stream) {
    const float* x  = (const float*)d_in[0];
    const float* wt = (const float*)d_in[1];
    float* out      = (float*)d_out;

    // zero page for D/H-pad staging sources (graph-capture-safe async memset)
    hipMemsetAsync(d_ws, 0, 4096, stream);

    // 1024 blocks = 8 XCD x 4 bc x 8 dout-pairs x 4 ho_tile ; 256 threads
    dim3 grid(1024), block(256);
    hipLaunchKernelGGL(lconv_kernel, grid, block, 0, stream, x, wt, out,
                       (const float*)d_ws);
}

// Round 8
// 65.820 us; speedup vs baseline: 1.1072x; 1.0503x over previous
//
#include <hip/hip_runtime.h>
#include <stdint.h>

// out[b, q*16+c, do,ho,wo] = sum_{kd,kh,kw} x[b, q*16+c, do+kd-1, ho+kh-1, wo+kw-1]
//                                           * weight[b, 0, c, (kd*3+kh)*3+kw, do,ho,wo]
// x: (2,64,16,64,64) f32; weight: (2,1,16,27,16,64,64) f32; out: (2,64,16,64,64) f32
//
// r5 structure (256 thr, 1 dout/block, 2-buffer ping-pong, stage-ahead-1,
// global_load_lds staging, 4 blocks/CU) + 1-deep weight register pipeline:
// 9 static dh-groups; group g computes with wreg[g&1] while prefetching
// group g+1 into wreg[(g+1)&1]. OOB d-planes staged from zero page (no branch).

#define NQ 4
typedef float f4_t __attribute__((ext_vector_type(4)));

#define BUF_FLOATS (NQ * 18 * 64)              // 4608 floats per plane-slab
#define LDS_FLOATS (16 + 2 * BUF_FLOATS + 16)  // guards for W-edge reads

__device__ __forceinline__ void async_copy16(const float* gsrc, float* ldst) {
    __builtin_amdgcn_global_load_lds(
        (const __attribute__((address_space(1))) uint32_t*)gsrc,
        (__attribute__((address_space(3))) uint32_t*)ldst, 16, 0, 0);
}

__global__ __launch_bounds__(256) void lconv_kernel(
    const float* __restrict__ x, const float* __restrict__ wt, float* __restrict__ out,
    const float* __restrict__ zp)
{
    __shared__ __align__(16) float lds_raw[LDS_FLOATS];

    const int tid = threadIdx.x;
    const int tw  = tid & 15;   // group of 4 wo
    const int th  = tid >> 4;   // ho row within tile

    // XCD-aware decode: bid&7 = XCD; all douts of a (b,c) run on one XCD ->
    // the 3x-read x planes stay in that XCD's L2.
    const int bid  = blockIdx.x;
    const int slot = bid >> 3;                  // 0..255
    const int bc   = (bid & 7) * 4 + (slot >> 6);
    const int dout = (slot >> 2) & 15;
    const int ho_tile = slot & 3;
    const int b = bc >> 4, c = bc & 15;

    const int ho_base = ho_tile * 16;
    const int ho  = ho_base + th;
    const int wo0 = tw * 4;

    const float* xbase = x + ((size_t)(b * 64 + c) * 16) * 4096;

    // stage plane d into buf: 1152 16B chunks, linear LDS dest; OOB -> zero page
    auto stage = [&](int buf, int d) {
        float* dbase = &lds_raw[16 + buf * BUF_FLOATS];
        #pragma unroll
        for (int it = 0; it < 5; ++it) {
            const int i = it * 256 + tid;
            if (it < 4 || i < 1152) {
                const int row = i >> 4;            // q*18 + hl
                const int seg = i & 15;
                const int q   = row / 18;
                const int hl  = row - q * 18;
                const int gh  = ho_base - 1 + hl;
                const bool ok = ((unsigned)d < 16u) && ((unsigned)gh < 64u);
                const float* src = ok
                    ? (xbase + (size_t)q * 1048576 + (size_t)d * 4096
                             + (size_t)gh * 64 + seg * 4)
                    : (zp + seg * 4);              // zero page: D-pad / H-pad
                async_copy16(src, dbase + (size_t)i * 4);
            }
        }
    };

    float acc[NQ][4];
    #pragma unroll
    for (int q = 0; q < NQ; ++q)
        #pragma unroll
        for (int j = 0; j < 4; ++j) acc[q][j] = 0.f;

    // weight base at k=0 ; group g covers k = g*3 .. g*3+2
    const float* wbase = wt + (((size_t)(b * 16 + c) * 27) * 16 + dout) * 4096
                            + (size_t)ho * 64 + wo0;

    f4_t wreg[2][3];   // static indices after full unroll of g-loop

    stage(0, dout - 1);                    // d=-1 handled by zero page
    #pragma unroll
    for (int dw = 0; dw < 3; ++dw)         // group 0 loads hide under barrier drain
        wreg[0][dw] = __builtin_nontemporal_load(
            reinterpret_cast<const f4_t*>(wbase + (size_t)dw * 65536));
    __syncthreads();

    #pragma unroll
    for (int g = 0; g < 9; ++g) {          // g = dd*3 + dh
        const int dd  = g / 3;
        const int dh  = g - dd * 3;
        const int cur = dd & 1;

        if (dh == 0 && dd < 2) stage(cur ^ 1, dout + dd);   // stage-ahead-1

        if (g < 8) {                        // prefetch next group's weights
            #pragma unroll
            for (int dw = 0; dw < 3; ++dw)
                wreg[(g + 1) & 1][dw] = __builtin_nontemporal_load(
                    reinterpret_cast<const f4_t*>(wbase + (size_t)((g + 1) * 3 + dw) * 65536));
        }

        const f4_t wa0 = wreg[g & 1][0];
        const f4_t wa1 = wreg[g & 1][1];
        const f4_t wa2 = wreg[g & 1][2];

        const float* r0 = &lds_raw[16 + cur * BUF_FLOATS] + (th + dh) * 64;

        #pragma unroll
        for (int q = 0; q < NQ; ++q) {
            const float* r = r0 + q * (18 * 64);
            const f4_t m  = *reinterpret_cast<const f4_t*>(r + wo0);
            const float xl = r[wo0 - 1];          // const offsets -> ds_read2
            const float xr = r[wo0 + 4];
            const float x0 = (tw > 0)  ? xl : 0.f;   // W-pad by value mask
            const float x5 = (tw < 15) ? xr : 0.f;
            // dw=0: xv[0..3] ; dw=1: xv[1..4] ; dw=2: xv[2..5]
            acc[q][0] = fmaf(x0,  wa0.x, acc[q][0]);
            acc[q][1] = fmaf(m.x, wa0.y, acc[q][1]);
            acc[q][2] = fmaf(m.y, wa0.z, acc[q][2]);
            acc[q][3] = fmaf(m.z, wa0.w, acc[q][3]);
            acc[q][0] = fmaf(m.x, wa1.x, acc[q][0]);
            acc[q][1] = fmaf(m.y, wa1.y, acc[q][1]);
            acc[q][2] = fmaf(m.z, wa1.z, acc[q][2]);
            acc[q][3] = fmaf(m.w, wa1.w, acc[q][3]);
            acc[q][0] = fmaf(m.y, wa2.x, acc[q][0]);
            acc[q][1] = fmaf(m.z, wa2.y, acc[q][1]);
            acc[q][2] = fmaf(m.w, wa2.z, acc[q][2]);
            acc[q][3] = fmaf(x5,  wa2.w, acc[q][3]);
        }

        if (dh == 2 && dd < 2) __syncthreads();   // section boundary: ping-pong safety
    }

    #pragma unroll
    for (int q = 0; q < NQ; ++q) {
        float* orow = out + ((size_t)(b * 64 + q * 16 + c) * 16 + dout) * 4096
                          + (size_t)ho * 64 + wo0;
        f4_t rr; rr.x = acc[q][0]; rr.y = acc[q][1]; rr.z = acc[q][2]; rr.w = acc[q][3];
        __builtin_nontemporal_store(rr, reinterpret_cast<f4_t*>(orow));
    }
}

extern "C" void kernel_launch(void* const* d_in, const int* in_sizes, int n_in,
                              void* d_out, int out_size, void* d_ws, size_t ws_size,
                              hipStream_t stream) {
    const float* x  = (const float*)d_in[0];
    const float* wt = (const float*)d_in[1];
    float* out      = (float*)d_out;

    // zero page for D/H-pad staging sources (graph-capture-safe async memset)
    hipMemsetAsync(d_ws, 0, 4096, stream);

    // 2048 blocks = 8 XCD x 4 bc x 16 dout x 4 ho_tile ; 256 threads
    dim3 grid(2048), block(256);
    hipLaunchKernelGGL(lconv_kernel, grid, block, 0, stream, x, wt, out,
                       (const float*)d_ws);
}

// Round 9
// 56.440 us; speedup vs baseline: 1.2913x; 1.1662x over previous
//
#include <hip/hip_runtime.h>
#include <stdint.h>

// out[b, q*16+c, do,ho,wo] = sum_{kd,kh,kw} x[b, q*16+c, do+kd-1, ho+kh-1, wo+kw-1]
//                                           * weight[b, 0, c, (kd*3+kh)*3+kw, do,ho,wo]
// x: (2,64,16,64,64) f32; weight: (2,1,16,27,16,64,64) f32; out: (2,64,16,64,64) f32
//
// r5 structure (1 dout/block, 2-buffer LDS ping-pong, 2048 blocks, 4 blocks/CU)
// + global_load_lds staging + value-masked edges + XCD-aware block decode.
// Best measured: 56.35 us (~6.6 TB/s of ~373 MB off-CU requests; fills = 7.0-7.2).

#define NQ 4
typedef float f4_t __attribute__((ext_vector_type(4)));

#define BUF_FLOATS (NQ * 18 * 64)              // 4608 floats / plane-slab
#define LDS_FLOATS (16 + 2 * BUF_FLOATS + 16)  // front/back guards for edge reads

__device__ __forceinline__ void async_copy16(const float* gsrc, float* ldst) {
    __builtin_amdgcn_global_load_lds(
        (const __attribute__((address_space(1))) uint32_t*)gsrc,
        (__attribute__((address_space(3))) uint32_t*)ldst, 16, 0, 0);
}

__global__ __launch_bounds__(256) void lconv_kernel(
    const float* __restrict__ x, const float* __restrict__ wt, float* __restrict__ out,
    const float* __restrict__ zp)
{
    __shared__ __align__(16) float lds_raw[LDS_FLOATS];

    const int tid = threadIdx.x;
    const int tw  = tid & 15;   // group of 4 wo
    const int th  = tid >> 4;   // ho row within tile

    // XCD-aware decode (dispatch round-robins bid over 8 XCDs): each XCD owns
    // 4 (b,c) slices; douts of one (b,c) run temporally adjacent -> the 3x
    // re-read x planes stay in that XCD's L2 (~2MB live < 4MB).
    const int bid  = blockIdx.x;
    const int slot = bid >> 3;
    const int bc   = (bid & 7) * 4 + (slot >> 6);   // 0..31
    const int dout = (slot >> 2) & 15;
    const int ho_tile = slot & 3;
    const int b = bc >> 4, c = bc & 15;

    const int ho_base = ho_tile * 16;
    const int ho  = ho_base + th;
    const int wo0 = tw * 4;

    // x base for (b,c): q adds 1048576 floats, d adds 4096 floats
    const float* xbase = x + ((size_t)(b * 64 + c) * 16) * 4096;

    // stage plane d into buf: 1152 16B chunks, linear LDS dest (wave base+lane*16)
    auto stage = [&](int buf, int d) {
        float* dbase = &lds_raw[16 + buf * BUF_FLOATS];
        #pragma unroll
        for (int it = 0; it < 5; ++it) {
            const int i = it * 256 + tid;          // chunk id
            if (it < 4 || i < 1152) {
                const int row = i >> 4;            // q*18 + hl
                const int seg = i & 15;
                const int q   = row / 18;
                const int hl  = row - q * 18;
                const int gh  = ho_base - 1 + hl;
                const float* src = ((unsigned)gh < 64u)
                    ? (xbase + (size_t)q * 1048576 + (size_t)d * 4096
                             + (size_t)gh * 64 + seg * 4)
                    : (zp + seg * 4);              // zero page for H-pad rows
                async_copy16(src, dbase + (size_t)i * 4);
            }
        }
    };

    float acc[NQ][4];
    #pragma unroll
    for (int q = 0; q < NQ; ++q)
        #pragma unroll
        for (int j = 0; j < 4; ++j) acc[q][j] = 0.f;

    // weight base at k=0
    const float* wbase = wt + (((size_t)(b * 16 + c) * 27) * 16 + dout) * 4096
                            + (size_t)ho * 64 + wo0;

    if (dout > 0) stage(0, dout - 1);
    __syncthreads();

    #pragma unroll
    for (int dd = 0; dd < 3; ++dd) {
        const int cur = dd & 1, nxt = cur ^ 1;
        if (dd < 2 && dout + dd < 16) stage(nxt, dout + dd);  // prefetch next plane

        const int d = dout + dd - 1;
        if ((unsigned)d < 16u) {                  // block-uniform
            const float* bbase = &lds_raw[16 + cur * BUF_FLOATS];
            #pragma unroll
            for (int dh = 0; dh < 3; ++dh) {
                float xv[NQ][6];
                #pragma unroll
                for (int q = 0; q < NQ; ++q) {
                    const float* r = bbase + (q * 18 + th + dh) * 64;
                    const f4_t m = *reinterpret_cast<const f4_t*>(r + wo0);
                    const float xl = r[wo0 - 1];   // constant offsets -> ds_read2
                    const float xr = r[wo0 + 4];
                    xv[q][0] = (tw > 0)  ? xl : 0.f;   // W-pad by value mask
                    xv[q][1] = m.x; xv[q][2] = m.y; xv[q][3] = m.z; xv[q][4] = m.w;
                    xv[q][5] = (tw < 15) ? xr : 0.f;
                }
                #pragma unroll
                for (int dw = 0; dw < 3; ++dw) {
                    const int k = (dd * 3 + dh) * 3 + dw;
                    const f4_t w4 = __builtin_nontemporal_load(
                        reinterpret_cast<const f4_t*>(wbase + (size_t)k * 65536));
                    #pragma unroll
                    for (int q = 0; q < NQ; ++q) {
                        acc[q][0] = fmaf(xv[q][0 + dw], w4.x, acc[q][0]);
                        acc[q][1] = fmaf(xv[q][1 + dw], w4.y, acc[q][1]);
                        acc[q][2] = fmaf(xv[q][2 + dw], w4.z, acc[q][2]);
                        acc[q][3] = fmaf(xv[q][3 + dw], w4.w, acc[q][3]);
                    }
                }
            }
        }
        if (dd < 2) __syncthreads();   // drains stage vmcnt + protects ping-pong
    }

    #pragma unroll
    for (int q = 0; q < NQ; ++q) {
        float* orow = out + ((size_t)(b * 64 + q * 16 + c) * 16 + dout) * 4096
                          + (size_t)ho * 64 + wo0;
        f4_t rr; rr.x = acc[q][0]; rr.y = acc[q][1]; rr.z = acc[q][2]; rr.w = acc[q][3];
        __builtin_nontemporal_store(rr, reinterpret_cast<f4_t*>(orow));
    }
}

extern "C" void kernel_launch(void* const* d_in, const int* in_sizes, int n_in,
                              void* d_out, int out_size, void* d_ws, size_t ws_size,
                              hipStream_t stream) {
    const float* x  = (const float*)d_in[0];
    const float* wt = (const float*)d_in[1];
    float* out      = (float*)d_out;

    // zero page for H-pad staging sources (graph-capture-safe async memset)
    hipMemsetAsync(d_ws, 0, 4096, stream);

    // 2048 blocks = 8 XCD x 4 bc x 16 dout x 4 ho_tile
    dim3 grid(2048), block(256);
    hipLaunchKernelGGL(lconv_kernel, grid, block, 0, stream, x, wt, out,
                       (const float*)d_ws);
}